// Round 4
// baseline (481.332 us; speedup 1.0000x reference)
//
#include <hip/hip_runtime.h>
#include <hip/hip_bf16.h>

#define NN 50000
#define EE 640000
#define NB 196  // ceil(NN/256)

typedef __attribute__((ext_vector_type(8))) short short8;
typedef __attribute__((ext_vector_type(4))) float f32x4;

__device__ __forceinline__ float bf2f(ushort u) {
    return __uint_as_float(((uint)u) << 16);
}
__device__ __forceinline__ ushort f2bf(float f) {
    uint b = __float_as_uint(f);
    uint r = (b + 0x7fffu + ((b >> 16) & 1u)) >> 16;
    return (ushort)r;
}
__device__ __forceinline__ ushort f2bf_rn(float f) {
    return (ushort)((__float_as_uint(f) + 0x8000u) >> 16);
}

// ---- CSR build ------------------------------------------------------------

__global__ __launch_bounds__(256) void k_hist(const int* __restrict__ ei,
                                              int* __restrict__ counts) {
    int e = blockIdx.x * 256 + threadIdx.x;
    if (e < EE) atomicAdd(&counts[ei[EE + e]], 1);
}

__global__ __launch_bounds__(256) void k_scan_a(const int* __restrict__ counts,
                                                int* __restrict__ bsum) {
    int i = blockIdx.x * 256 + threadIdx.x;
    int v = (i < NN) ? counts[i] : 0;
    #pragma unroll
    for (int o = 32; o > 0; o >>= 1) v += __shfl_xor(v, o);
    __shared__ int ws[4];
    if ((threadIdx.x & 63) == 0) ws[threadIdx.x >> 6] = v;
    __syncthreads();
    if (threadIdx.x == 0) bsum[blockIdx.x] = ws[0] + ws[1] + ws[2] + ws[3];
}

__global__ __launch_bounds__(256) void k_scan_b(const int* __restrict__ bsum,
                                                int* __restrict__ boff,
                                                int* __restrict__ offs) {
    const int t = threadIdx.x;
    const int lane = t & 63, wave = t >> 6;
    int v = (t < NB) ? bsum[t] : 0;
    int x = v;
    #pragma unroll
    for (int o = 1; o < 64; o <<= 1) {
        int y = __shfl_up(x, o);
        if (lane >= o) x += y;
    }
    __shared__ int ws[4];
    if (lane == 63) ws[wave] = x;
    __syncthreads();
    int add = 0;
    for (int w = 0; w < wave; ++w) add += ws[w];
    x += add;
    if (t < NB) boff[t] = x - v;
    if (t == 255) offs[NN] = x;
}

__global__ __launch_bounds__(256) void k_scan_c(const int* __restrict__ counts,
                                                const int* __restrict__ boff,
                                                int* __restrict__ offs,
                                                int* __restrict__ cursor) {
    int i = blockIdx.x * 256 + threadIdx.x;
    const int lane = threadIdx.x & 63, wave = threadIdx.x >> 6;
    int v = (i < NN) ? counts[i] : 0;
    int x = v;
    #pragma unroll
    for (int o = 1; o < 64; o <<= 1) {
        int y = __shfl_up(x, o);
        if (lane >= o) x += y;
    }
    __shared__ int ws[4];
    if (lane == 63) ws[wave] = x;
    __syncthreads();
    int add = boff[blockIdx.x];
    for (int w = 0; w < wave; ++w) add += ws[w];
    int ex = add + x - v;
    if (i < NN) {
        offs[i] = ex;
        cursor[i] = ex;
    }
}

__global__ __launch_bounds__(256) void k_scatter(const int* __restrict__ ei,
                                                 const float* __restrict__ ea,
                                                 int* __restrict__ cursor,
                                                 uint2* __restrict__ adj,
                                                 uint* __restrict__ adst) {
    int e = blockIdx.x * 256 + threadIdx.x;
    if (e >= EE) return;
    int d = ei[EE + e];
    int pos = atomicAdd(&cursor[d], 1);
    ushort lo = f2bf(ea[2 * e]);
    ushort hi = f2bf(ea[2 * e + 1]);
    adj[pos] = make_uint2((uint)ei[e], ((uint)hi << 16) | (uint)lo);
    adst[pos] = (uint)d;
}

// ---- Weight composition ---------------------------------------------------

__global__ __launch_bounds__(256) void k_compose(const float* __restrict__ wn_all,
                                                 const float* __restrict__ aw1,
                                                 const float* __restrict__ wle,
                                                 ushort* __restrict__ wcT) {
    const int l = blockIdx.x >> 7;
    const int k = blockIdx.x & 127;
    const int t = threadIdx.x;
    const float* wn = wn_all + (l * 128 + k) * 128;
    float acc = 0.f;
    for (int c = 0; c < 128; ++c) {
        float cat;
        if (t < 128)
            cat = aw1[(l * 256 + ((t & 64) << 1) + c) * 64 + (t & 63)];
        else
            cat = wle[(l * 130 + c) * 128 + (t - 128)];
        acc += wn[c] * cat;
    }
    wcT[(l * 256 + t) * 128 + k] = f2bf(acc);
}

// ---- K1: pqr = x @ Wc   [N,128]x[128,256] -> bf16 [N,256] -----------------

__global__ __launch_bounds__(256) void k1_gemm(const float* __restrict__ xin,
                                               const ushort* __restrict__ wcT,
                                               ushort* __restrict__ pqr) {
    const int wave = threadIdx.x >> 6;
    const int lane = threadIdx.x & 63;
    const int r0 = blockIdx.x * 16;
    const int c0 = wave * 64;
    const int lrow = lane & 15;
    const int kg = lane >> 4;

    const float* xrow = xin + (r0 + lrow) * 128;
    short8 a[4];
    #pragma unroll
    for (int s = 0; s < 4; ++s) {
        const float* px = xrow + s * 32 + kg * 8;
        float4 u = *(const float4*)(px);
        float4 v = *(const float4*)(px + 4);
        short8 av;
        av[0] = (short)f2bf(u.x); av[1] = (short)f2bf(u.y);
        av[2] = (short)f2bf(u.z); av[3] = (short)f2bf(u.w);
        av[4] = (short)f2bf(v.x); av[5] = (short)f2bf(v.y);
        av[6] = (short)f2bf(v.z); av[7] = (short)f2bf(v.w);
        a[s] = av;
    }

    f32x4 acc[4] = {};
    #pragma unroll
    for (int t = 0; t < 4; ++t) {
        const int col = c0 + t * 16 + lrow;
        #pragma unroll
        for (int s = 0; s < 4; ++s) {
            short8 b = *(const short8*)(wcT + col * 128 + s * 32 + kg * 8);
            acc[t] = __builtin_amdgcn_mfma_f32_16x16x32_bf16(a[s], b, acc[t], 0, 0, 0);
        }
    }
    #pragma unroll
    for (int t = 0; t < 4; ++t) {
        const int col = c0 + t * 16 + lrow;
        #pragma unroll
        for (int j = 0; j < 4; ++j) {
            pqr[(r0 + kg * 4 + j) * 256 + col] = f2bf(acc[t][j]);
        }
    }
}

// ---- K_att: edge-parallel attention scores via MFMA -----------------------
// One wave = 64 edges = 4 MFMA tiles sharing one B fragment (col0 = w2).

__global__ __launch_bounds__(256) void k_att(const uint2* __restrict__ adj,
                                             const uint* __restrict__ adst,
                                             const ushort* __restrict__ pqr,
                                             const float* __restrict__ b1v,
                                             const float* __restrict__ w2v,
                                             const float* __restrict__ b2v,
                                             float* __restrict__ attv) {
    const int lane = threadIdx.x & 63;
    const int e0 = blockIdx.x * 256 + (threadIdx.x >> 6) * 64;
    const int row = lane & 15;
    const int kg = lane >> 4;
    const float b2 = b2v[0];

    short8 bv0, bv1;
    const bool col0 = (row == 0);
    #pragma unroll
    for (int j = 0; j < 8; ++j) {
        bv0[j] = (short)f2bf(col0 ? w2v[kg * 8 + j] : 0.f);
        bv1[j] = (short)f2bf(col0 ? w2v[32 + kg * 8 + j] : 0.f);
    }

    uint srcs[4], dsts[4];
    #pragma unroll
    for (int t = 0; t < 4; ++t) {
        const int eidx = e0 + t * 16 + row;
        srcs[t] = adj[eidx].x;
        dsts[t] = adst[eidx];
    }

    f32x4 acc[4] = {};
    #pragma unroll
    for (int h = 0; h < 2; ++h) {
        const int cb = 32 * h + kg * 8;
        float4 bA = *(const float4*)(b1v + cb);
        float4 bB = *(const float4*)(b1v + cb + 4);
        const short8 bfrag = h ? bv1 : bv0;
        #pragma unroll
        for (int t = 0; t < 4; ++t) {
            short8 qv = *(const short8*)(pqr + (size_t)srcs[t] * 256 + 64 + cb);
            short8 pv = *(const short8*)(pqr + (size_t)dsts[t] * 256 + cb);
            short8 av;
            #pragma unroll
            for (int j = 0; j < 8; ++j) {
                float bb = (j < 4) ? ((const float*)&bA)[j] : ((const float*)&bB)[j - 4];
                float v = bf2f((ushort)qv[j]) + bf2f((ushort)pv[j]) + bb;
                av[j] = (short)f2bf_rn(fmaxf(v, 0.f));
            }
            acc[t] = __builtin_amdgcn_mfma_f32_16x16x32_bf16(av, bfrag, acc[t], 0, 0, 0);
        }
    }
    if (row == 0) {
        #pragma unroll
        for (int t = 0; t < 4; ++t) {
            float4 o;
            #pragma unroll
            for (int j = 0; j < 4; ++j) {
                float s = acc[t][j] + b2;
                ((float*)&o)[j] = 1.f / (1.f + __expf(-s));
            }
            *(float4*)(attv + e0 + t * 16 + kg * 4) = o;
        }
    }
}

// ---- K_msg: 3-stage software-pipelined aggregation + epilogue -------------
// Chunks of D=8 edges; meta prefetched 2 chunks ahead, r-gathers 1 ahead.
// Out-of-range slots predicated via att=0 (branchless); guards wave-uniform.

__global__ __launch_bounds__(256) void k_msg(
    const int* __restrict__ offs, const uint2* __restrict__ adj,
    const float* __restrict__ attv, const ushort* __restrict__ pqr,
    const float* __restrict__ xin, const float* __restrict__ web,
    const float* __restrict__ biasv, const float* __restrict__ gammav,
    const float* __restrict__ betav, float* __restrict__ xout, int do_relu) {
    const int lane = threadIdx.x & 63;
    const int n = blockIdx.x * 4 + (threadIdx.x >> 6);
    const int c0 = 2 * lane;

    // hoisted uniform/epilogue loads
    const float web00 = web[c0], web01 = web[c0 + 1];
    const float web10 = web[128 + c0], web11 = web[128 + c0 + 1];
    const float2 xr = *(const float2*)(xin + (size_t)n * 128 + c0);
    const float2 bi = *(const float2*)(biasv + c0);
    const float2 ga = *(const float2*)(gammav + c0);
    const float2 be = *(const float2*)(betav + c0);

    const int eb = offs[n], ee = offs[n + 1];
    const int cnt = ee - eb;
    float acc0 = 0.f, acc1 = 0.f, sE0 = 0.f, sE1 = 0.f;

    if (cnt > 0) {
        constexpr int D = 8;
        uint Y0[D]; float A0[D]; uint R0[D];
        uint Y1[D]; float A1[D]; uint S1[D];
        {
            uint S0[D];
            #pragma unroll
            for (int d = 0; d < D; ++d) {
                const int idx = (d < cnt) ? (eb + d) : eb;
                const uint2 m = adj[idx];
                Y0[d] = m.y; S0[d] = m.x;
                A0[d] = (d < cnt) ? attv[idx] : 0.f;
            }
            #pragma unroll
            for (int d = 0; d < D; ++d)
                R0[d] = *(const uint*)(pqr + (size_t)S0[d] * 256 + 128 + c0);
        }
        #pragma unroll
        for (int d = 0; d < D; ++d) {
            const int j = D + d;
            const int idx = (j < cnt) ? (eb + j) : eb;
            const uint2 m = adj[idx];
            Y1[d] = m.y; S1[d] = m.x;
            A1[d] = (j < cnt) ? attv[idx] : 0.f;
        }

        for (int i = 0;;) {
            const bool more = (i + D) < cnt;  // wave-uniform
            uint R1[D]; uint Y2[D]; float A2[D]; uint S2[D];
            if (more) {
                #pragma unroll
                for (int d = 0; d < D; ++d)
                    R1[d] = *(const uint*)(pqr + (size_t)S1[d] * 256 + 128 + c0);
                #pragma unroll
                for (int d = 0; d < D; ++d) {
                    const int j = i + 2 * D + d;
                    const int idx = (j < cnt) ? (eb + j) : eb;
                    const uint2 m = adj[idx];
                    Y2[d] = m.y; S2[d] = m.x;
                    A2[d] = (j < cnt) ? attv[idx] : 0.f;
                }
            }
            #pragma unroll
            for (int d = 0; d < D; ++d) {
                const float a = A0[d];
                acc0 = fmaf(a, __uint_as_float(R0[d] << 16), acc0);
                acc1 = fmaf(a, __uint_as_float(R0[d] & 0xffff0000u), acc1);
                sE0  = fmaf(a, __uint_as_float(Y0[d] << 16), sE0);
                sE1  = fmaf(a, __uint_as_float(Y0[d] & 0xffff0000u), sE1);
            }
            i += D;
            if (i >= cnt) break;
            #pragma unroll
            for (int d = 0; d < D; ++d) {
                Y0[d] = Y1[d]; A0[d] = A1[d]; R0[d] = R1[d];
                Y1[d] = Y2[d]; A1[d] = A2[d]; S1[d] = S2[d];
            }
        }
        acc0 += sE0 * web00 + sE1 * web10;
        acc1 += sE0 * web01 + sE1 * web11;
    }

    float v0 = acc0 + bi.x;
    float v1 = acc1 + bi.y;
    float sm = v0 + v1, sq = v0 * v0 + v1 * v1;
    #pragma unroll
    for (int o = 32; o > 0; o >>= 1) {
        sm += __shfl_xor(sm, o);
        sq += __shfl_xor(sq, o);
    }
    const float mean = sm * (1.f / 128.f);
    const float var = sq * (1.f / 128.f) - mean * mean;
    const float inv = rsqrtf(var + 1e-5f);
    float y0 = (v0 - mean) * inv * ga.x + be.x;
    float y1 = (v1 - mean) * inv * ga.y + be.y;
    if (do_relu) { y0 = fmaxf(y0, 0.f); y1 = fmaxf(y1, 0.f); }
    y0 += xr.x;
    y1 += xr.y;
    float2 o2; o2.x = y0; o2.y = y1;
    *(float2*)(xout + (size_t)n * 128 + c0) = o2;
}

// ---------------------------------------------------------------------------

extern "C" void kernel_launch(void* const* d_in, const int* in_sizes, int n_in,
                              void* d_out, int out_size, void* d_ws, size_t ws_size,
                              hipStream_t stream) {
    const float* x   = (const float*)d_in[0];
    const int*   ei  = (const int*)d_in[1];
    const float* ea  = (const float*)d_in[2];
    const float* wn  = (const float*)d_in[3];
    const float* wle = (const float*)d_in[4];
    const float* aw1 = (const float*)d_in[5];
    const float* ab1 = (const float*)d_in[6];
    const float* aw2 = (const float*)d_in[7];
    const float* ab2 = (const float*)d_in[8];
    const float* bia = (const float*)d_in[9];
    const float* gam = (const float*)d_in[10];
    const float* bet = (const float*)d_in[11];

    char* w = (char*)d_ws;
    size_t o = 0;
    auto alloc = [&](size_t bytes) {
        char* p = w + o;
        o = (o + bytes + 255) & ~(size_t)255;
        return p;
    };
    int*    counts = (int*)alloc((size_t)NN * 4);
    int*    offs   = (int*)alloc((size_t)(NN + 1) * 4);
    int*    cursor = (int*)alloc((size_t)NN * 4);
    int*    bsum   = (int*)alloc((size_t)NB * 4);
    int*    boff   = (int*)alloc((size_t)NB * 4);
    uint2*  adj    = (uint2*)alloc((size_t)EE * 8);
    uint*   adst   = (uint*)alloc((size_t)EE * 4);
    float*  attv   = (float*)alloc((size_t)EE * 4);
    ushort* wcT    = (ushort*)alloc((size_t)3 * 256 * 128 * 2);
    ushort* pqr    = (ushort*)alloc((size_t)NN * 256 * 2);
    float*  xb1    = (float*)alloc((size_t)NN * 128 * 4);
    float*  xb2    = (float*)alloc((size_t)NN * 128 * 4);

    hipMemsetAsync(counts, 0, (size_t)NN * 4, stream);
    k_hist<<<(EE + 255) / 256, 256, 0, stream>>>(ei, counts);
    k_scan_a<<<NB, 256, 0, stream>>>(counts, bsum);
    k_scan_b<<<1, 256, 0, stream>>>(bsum, boff, offs);
    k_scan_c<<<NB, 256, 0, stream>>>(counts, boff, offs, cursor);
    k_scatter<<<(EE + 255) / 256, 256, 0, stream>>>(ei, ea, cursor, adj, adst);
    k_compose<<<384, 256, 0, stream>>>(wn, aw1, wle, wcT);

    const float* xi = x;
    float* xo = xb1;
    for (int l = 0; l < 3; ++l) {
        k1_gemm<<<NN / 16, 256, 0, stream>>>(xi, wcT + (size_t)l * 256 * 128, pqr);
        k_att<<<EE / 256, 256, 0, stream>>>(adj, adst, pqr,
                                            ab1 + l * 64, aw2 + l * 64, ab2 + l, attv);
        const bool last = (l == 2);
        float* out_ptr = last ? (float*)d_out : xo;
        k_msg<<<NN / 4, 256, 0, stream>>>(
            offs, adj, attv, pqr, xi,
            wle + ((size_t)l * 130 + 128) * 128,
            bia + l * 128, gam + l * 128, bet + l * 128,
            out_ptr, last ? 0 : 1);
        xi = out_ptr;
        xo = (l == 0) ? xb2 : xb1;
    }
}